// Round 7
// baseline (400.578 us; speedup 1.0000x reference)
//
#include <hip/hip_runtime.h>

#define VOCAB 65536
#define NELEM 4194304      // 256*16*32*32
#define BHW   262144       // 256*1024

__device__ __forceinline__ double cubic_d(double t) {
  const double a = -0.75;
  t = fabs(t);
  if (t <= 1.0) return ((a + 2.0) * t - (a + 3.0)) * t * t + 1.0;
  if (t < 2.0)  return a * (((t - 5.0) * t + 8.0) * t - 4.0);
  return 0.0;
}

// PN=32 idx slot: XOR swizzle -> conflict-free for both writes (fixed y, varying x)
// and reads (fixed x, varying y). Bijective in (x,y).
__device__ __forceinline__ int idx32_slot(int x, int y) { return (x << 5) | ((y ^ x) & 31); }

// thread map (1024 threads): xq=t&7 (4-x strip, x0=4*xq), y=(t>>3)&31, g=t>>8
// owns channels 4g..4g+3. fhat[cc][k] = f_hat(c=4g+cc, y, x=4*xq+k) in f64.
// NO other per-thread f64 state survives across phases -> fits the 64-VGPR cap.
template<int PN>
__device__ __forceinline__ void process_scale(
    int si, int phi_idx, bool load_w,
    const float* __restrict__ f, const float* __restrict__ phi_w,
    const float* __restrict__ phi_b, float* __restrict__ hist,
    double* __restrict__ acc, double (&fhat)[4][4],
    double* __restrict__ hupd, float* __restrict__ wlds,
    unsigned* __restrict__ idxL, float* __restrict__ wMb, float* __restrict__ wMT,
    float* __restrict__ bias16, double* __restrict__ red,
    int t, int y, int g, int x0, size_t ibase)
{
  constexpr int CELLS = PN * PN;
  constexpr int S = 32 / PN;

  // ---------- P0: zero idx, (re)load weights, wM, stage resid ----------
  idxL[t] = 0u;
  if (load_w) {
    for (int i = t; i < 2304; i += 1024) wlds[i] = phi_w[phi_idx * 2304 + i];
    if (t < 16) bias16[t] = phi_b[phi_idx * 16 + t];
  }
  if constexpr (PN != 32) {
    if (t < 32) {
      float wrow[PN];
      #pragma unroll
      for (int q = 0; q < PN; ++q) wrow[q] = 0.0f;
      double xp = ((double)t + 0.5) * (double)PN / 32.0 - 0.5;
      int q0 = (int)floor(xp);
      for (int k = 0; k < 4; ++k) {
        int j = q0 + k - 1;
        int jc = j < 0 ? 0 : (j > PN - 1 ? PN - 1 : j);
        wrow[jc] += (float)cubic_d(xp - (double)j);   // f32 accumulate == np M build
      }
      #pragma unroll
      for (int q = 0; q < PN; ++q) { wMb[t * PN + q] = wrow[q]; wMT[q * 32 + t] = wrow[q]; }
    }
    #pragma unroll
    for (int cc = 0; cc < 4; ++cc) {
      const float4 fv = *(const float4*)(f + ibase + (size_t)(4 * g + cc) * 1024 + y * 32 + x0);
      double* hp = hupd + (4 * g + cc) * 1056 + y * 33 + x0;
      hp[0] = (double)fv.x - fhat[cc][0];
      hp[1] = (double)fv.y - fhat[cc][1];
      hp[2] = (double)fv.z - fhat[cc][2];
      hp[3] = (double)fv.w - fhat[cc][3];
    }
  }
  __syncthreads();

  // ---------- P2: quantize (sign of f64 cell sums) -> idxL ----------
  if constexpr (PN == 32) {
    unsigned bb[4] = {0u, 0u, 0u, 0u};
    #pragma unroll
    for (int cc = 0; cc < 4; ++cc) {
      const float4 fv = *(const float4*)(f + ibase + (size_t)(4 * g + cc) * 1024 + y * 32 + x0);
      if ((double)fv.x - fhat[cc][0] > 0.0) bb[0] |= (1u << cc);
      if ((double)fv.y - fhat[cc][1] > 0.0) bb[1] |= (1u << cc);
      if ((double)fv.z - fhat[cc][2] > 0.0) bb[2] |= (1u << cc);
      if ((double)fv.w - fhat[cc][3] > 0.0) bb[3] |= (1u << cc);
    }
    #pragma unroll
    for (int k = 0; k < 4; ++k)
      if (bb[k]) atomicOr(&idxL[idx32_slot(x0 + k, y)], bb[k] << (4 * g));
  } else if constexpr (PN == 16) {
    int cell = t & 255;
    int i0 = (cell >> 4) * 2, j0 = (cell & 15) * 2;
    unsigned bits = 0;
    #pragma unroll
    for (int k = 0; k < 4; ++k) {
      int c = (t >> 8) + 4 * k;
      const double* hp = hupd + c * 1056 + i0 * 33 + j0;
      double s = hp[0] + hp[1] + hp[33] + hp[34];
      if (s > 0.0) bits |= (1u << c);
    }
    atomicOr(&idxL[cell], bits);
  } else if constexpr (PN == 8) {
    int c = t >> 6, cell = t & 63;
    const double* hp = hupd + c * 1056 + ((cell >> 3) * 4) * 33 + (cell & 7) * 4;
    double s = 0.0;
    #pragma unroll
    for (int dy = 0; dy < 4; ++dy)
      #pragma unroll
      for (int dx = 0; dx < 4; ++dx) s += hp[dy * 33 + dx];
    if (s > 0.0) atomicOr(&idxL[cell], 1u << c);
  } else {   // PN 1,2,4
    constexpr int TASKS = 16 * CELLS;
    constexpr int G = 1024 / TASKS;       // 64, 16, 4
    int p = t / G, sub = t % G;
    int c = p / CELLS, cell = p % CELLS;
    const double* hp = hupd + c * 1056 + ((cell / PN) * S) * 33 + (cell % PN) * S;
    double s = 0.0;
    for (int e = sub; e < S * S; e += G) {
      int dy = e / S, dx = e % S;
      s += hp[dy * 33 + dx];
    }
    #pragma unroll
    for (int off = G / 2; off > 0; off >>= 1) s += __shfl_down(s, off, G);
    if (sub == 0 && s > 0.0) atomicOr(&idxL[cell], 1u << c);
  }
  __syncthreads();

  // ---------- P3: hist + upsample codes -> hupd ----------
  if constexpr (PN == 32) {
    atomicAdd(&hist[5 * VOCAB + idxL[t]], 1.0f);   // swizzle is bijective
  } else {
    if (t < CELLS) atomicAdd(&hist[(size_t)si * VOCAB + idxL[t]], 1.0f);
  }
  {
    int c2 = t >> 6, sub = (t >> 5) & 1, y2 = t & 31;
    double* hrow = hupd + c2 * 1056 + y2 * 33;
    if constexpr (PN == 32) {
      #pragma unroll
      for (int xi = 0; xi < 16; ++xi) {
        int x = 16 * sub + xi;
        hrow[x] = ((idxL[idx32_slot(x, y2)] >> c2) & 1) ? 1.0 : -1.0;
      }
    } else if constexpr (PN == 16) {
      // two q-half passes (tmp[8] not tmp[16]) continuing the SAME fma chain
      // through hrow -> accumulation order bit-identical to a single q-loop.
      double tmp[8];
      #pragma unroll
      for (int q = 0; q < 8; ++q) tmp[q] = 0.0;
      #pragma unroll
      for (int r = 0; r < 16; ++r) {
        double w = (double)wMT[r * 32 + y2];
        #pragma unroll
        for (int q = 0; q < 8; ++q) {
          double sg = ((idxL[r * 16 + q] >> c2) & 1) ? 1.0 : -1.0;
          tmp[q] = fma(w, sg, tmp[q]);
        }
      }
      #pragma unroll
      for (int xi = 0; xi < 16; ++xi) {
        int x = 16 * sub + xi;
        double s2 = 0.0;
        #pragma unroll
        for (int q = 0; q < 8; ++q) s2 = fma((double)wMb[x * 16 + q], tmp[q], s2);
        hrow[x] = s2;
      }
      #pragma unroll
      for (int q = 0; q < 8; ++q) tmp[q] = 0.0;
      #pragma unroll
      for (int r = 0; r < 16; ++r) {
        double w = (double)wMT[r * 32 + y2];
        #pragma unroll
        for (int q = 0; q < 8; ++q) {
          double sg = ((idxL[r * 16 + 8 + q] >> c2) & 1) ? 1.0 : -1.0;
          tmp[q] = fma(w, sg, tmp[q]);
        }
      }
      #pragma unroll
      for (int xi = 0; xi < 16; ++xi) {
        int x = 16 * sub + xi;
        double s2 = hrow[x];
        #pragma unroll
        for (int q = 0; q < 8; ++q) s2 = fma((double)wMb[x * 16 + 8 + q], tmp[q], s2);
        hrow[x] = s2;
      }
    } else {
      double tmp[PN];
      #pragma unroll
      for (int q = 0; q < PN; ++q) tmp[q] = 0.0;
      #pragma unroll
      for (int r = 0; r < PN; ++r) {
        double w = (double)wMT[r * 32 + y2];
        #pragma unroll
        for (int q = 0; q < PN; ++q) {
          double sg = ((idxL[r * PN + q] >> c2) & 1) ? 1.0 : -1.0;
          tmp[q] = fma(w, sg, tmp[q]);
        }
      }
      #pragma unroll
      for (int xi = 0; xi < 16; ++xi) {
        int x = 16 * sub + xi;
        double s2 = 0.0;
        #pragma unroll
        for (int q = 0; q < PN; ++q) s2 = fma((double)wMb[x * PN + q], tmp[q], s2);
        hrow[x] = s2;
      }
    }
  }
  __syncthreads();

  // ---------- P4a: entropy + psum (pre-update resid) + seed fhat ----------
  float entf = 0.0f;
  float ps[4] = {0.0f, 0.0f, 0.0f, 0.0f};
  #pragma unroll
  for (int cc = 0; cc < 4; ++cc) {
    int c = 4 * g + cc;
    double bh = 0.5 * (double)bias16[c];
    const double* hu = hupd + c * 1056 + y * 33 + x0;
    const float4 fv = *(const float4*)(f + ibase + (size_t)c * 1024 + y * 32 + x0);
    float fvk[4] = {fv.x, fv.y, fv.z, fv.w};
    float psl = 0.0f;
    #pragma unroll
    for (int k = 0; k < 4; ++k) {
      double xr = (double)fvk[k] - fhat[cc][k];            // residual BEFORE update
      float pr = 1.0f / (1.0f + __expf(400.0f * (float)xr));   // sigmoid(-400 x)
      entf -= pr * __logf(pr + 1e-5f) + (1.0f - pr) * __logf(1.0f - pr + 1e-5f);
      psl += pr;
      fhat[cc][k] = fhat[cc][k] + 0.5 * hu[k] + bh;        // seed: 0.5*hup + 0.5*bias
    }
    ps[cc] = psl;
  }

  // ---------- P4b: conv3x3 accumulated DIRECTLY into fhat (0.5-scaled weights) ----------
  for (int ci = 0; ci < 16; ++ci) {
    const double* hbase = hupd + ci * 1056;
    #pragma unroll
    for (int dy = 0; dy < 3; ++dy) {
      int ry = y + dy - 1;
      if (ry < 0 || ry > 31) continue;
      double prow[6];
      const double* hr = hbase + ry * 33;
      #pragma unroll
      for (int jj = 0; jj < 6; ++jj) {
        int xx = x0 - 1 + jj;
        prow[jj] = (xx < 0 || xx > 31) ? 0.0 : hr[xx];
      }
      #pragma unroll
      for (int cc = 0; cc < 4; ++cc) {
        const float* wp = wlds + (((4 * g + cc) * 16 + ci) * 9 + dy * 3);
        double w0 = 0.5 * (double)wp[0], w1 = 0.5 * (double)wp[1], w2 = 0.5 * (double)wp[2];
        #pragma unroll
        for (int k = 0; k < 4; ++k)
          fhat[cc][k] = fma(w0, prow[k], fma(w1, prow[k + 1], fma(w2, prow[k + 2], fhat[cc][k])));
      }
    }
  }

  // ---------- P4c: mse on updated fhat ----------
  double mse = 0.0;
  #pragma unroll
  for (int cc = 0; cc < 4; ++cc) {
    const float4 fv = *(const float4*)(f + ibase + (size_t)(4 * g + cc) * 1024 + y * 32 + x0);
    float fvk[4] = {fv.x, fv.y, fv.z, fv.w};
    #pragma unroll
    for (int k = 0; k < 4; ++k) {
      double d = fhat[cc][k] - (double)fvk[k];
      mse += d * d;
    }
  }

  double ent_d = (double)entf;
  #pragma unroll
  for (int off = 32; off > 0; off >>= 1) {
    mse   += __shfl_down(mse, off);
    ent_d += __shfl_down(ent_d, off);
    ps[0] += __shfl_down(ps[0], off);
    ps[1] += __shfl_down(ps[1], off);
    ps[2] += __shfl_down(ps[2], off);
    ps[3] += __shfl_down(ps[3], off);
  }
  int w = t >> 6;
  if ((t & 63) == 0) {
    red[w * 6 + 0] = mse;
    red[w * 6 + 1] = ent_d;
    red[w * 6 + 2] = (double)ps[0];
    red[w * 6 + 3] = (double)ps[1];
    red[w * 6 + 4] = (double)ps[2];
    red[w * 6 + 5] = (double)ps[3];
  }
  __syncthreads();

  // ---------- P5: block totals -> global acc ----------
  if (t == 0) {
    double m = 0.0, e = 0.0;
    #pragma unroll
    for (int ww = 0; ww < 16; ++ww) { m += red[ww * 6]; e += red[ww * 6 + 1]; }
    atomicAdd(&acc[si * 18 + 0], m);
    atomicAdd(&acc[si * 18 + 1], e);
  }
  if (t < 16) {
    // channel t = 4*gg + cc is produced by waves 4*gg .. 4*gg+3 (4 waves per g)
    int gg = t >> 2, cc = t & 3;
    double p = red[(4 * gg + 0) * 6 + 2 + cc] + red[(4 * gg + 1) * 6 + 2 + cc]
             + red[(4 * gg + 2) * 6 + 2 + cc] + red[(4 * gg + 3) * 6 + 2 + cc];
    atomicAdd(&acc[si * 18 + 2 + t], p);
  }
  __syncthreads();
}

__global__
__attribute__((amdgpu_flat_work_group_size(1024, 1024), amdgpu_waves_per_eu(4, 4)))
void lfq_all(
    const float* __restrict__ f, const float* __restrict__ phi_w,
    const float* __restrict__ phi_b, float* __restrict__ fhi,
    float* __restrict__ hist, double* __restrict__ acc)
{
  __shared__ double   hupd[16 * 1056];   // 135168 B: resid / upsampled codes
  __shared__ float    wlds[2304];        // conv weights
  __shared__ unsigned idxL[1024];        // codes per cell (XOR-swizzled for PN=32)
  __shared__ float    wMb[512];          // bicubic M [32][PN]
  __shared__ float    wMT[512];          // transposed [PN][32]
  __shared__ float    bias16[16];
  __shared__ double   red[96];           // 16 waves x 6 slots

  const int t = threadIdx.x;
  const int y = (t >> 3) & 31, g = t >> 8;
  const int x0 = (t & 7) * 4;
  const size_t ibase = (size_t)blockIdx.x * 16384;

  double fhat[4][4];
  #pragma unroll
  for (int cc = 0; cc < 4; ++cc)
    #pragma unroll
    for (int k = 0; k < 4; ++k) fhat[cc][k] = 0.0;

  // PHI_IDX = [0,0,1,2,3,3]
  process_scale<1 >(0, 0, true,  f, phi_w, phi_b, hist, acc, fhat, hupd, wlds, idxL, wMb, wMT, bias16, red, t, y, g, x0, ibase);
  process_scale<2 >(1, 0, false, f, phi_w, phi_b, hist, acc, fhat, hupd, wlds, idxL, wMb, wMT, bias16, red, t, y, g, x0, ibase);
  process_scale<4 >(2, 1, true,  f, phi_w, phi_b, hist, acc, fhat, hupd, wlds, idxL, wMb, wMT, bias16, red, t, y, g, x0, ibase);
  process_scale<8 >(3, 2, true,  f, phi_w, phi_b, hist, acc, fhat, hupd, wlds, idxL, wMb, wMT, bias16, red, t, y, g, x0, ibase);
  process_scale<16>(4, 3, true,  f, phi_w, phi_b, hist, acc, fhat, hupd, wlds, idxL, wMb, wMT, bias16, red, t, y, g, x0, ibase);
  process_scale<32>(5, 3, false, f, phi_w, phi_b, hist, acc, fhat, hupd, wlds, idxL, wMb, wMT, bias16, red, t, y, g, x0, ibase);

  #pragma unroll
  for (int cc = 0; cc < 4; ++cc) {
    float* op = fhi + ibase + (size_t)(4 * g + cc) * 1024 + y * 32 + x0;
    #pragma unroll
    for (int k = 0; k < 4; ++k) op[k] = (float)fhat[cc][k];
  }
}

__global__ void finalize_total(const double* __restrict__ acc, float* __restrict__ total)
{
  if (threadIdx.x == 0 && blockIdx.x == 0) {
    double vq = 0.0, ent = 0.0;
    for (int si = 0; si < 6; ++si) {
      vq += acc[si * 18 + 0];
      double pse = acc[si * 18 + 1] / (double)BHW;
      double ce = 0.0;
      for (int cc = 0; cc < 16; ++cc) {
        double ap0 = acc[si * 18 + 2 + cc] / (double)BHW;
        double ap1 = 1.0 - ap0;
        ce -= ap0 * log(ap0 + 1e-5) + ap1 * log(ap1 + 1e-5);
      }
      ent += pse - ce;
    }
    *total = (float)(1.25 * vq / ((double)NELEM * 6.0) + (0.1 / 6.0) * ent);
  }
}

extern "C" void kernel_launch(void* const* d_in, const int* in_sizes, int n_in,
                              void* d_out, int out_size, void* d_ws, size_t ws_size,
                              hipStream_t stream)
{
  const float* f     = (const float*)d_in[0];
  const float* phi_w = (const float*)d_in[1];
  const float* phi_b = (const float*)d_in[2];
  float* out   = (float*)d_out;
  float* fhi   = out;                 // [0, NELEM) — fully overwritten
  float* total = out + NELEM;
  float* hist  = out + NELEM + 1;     // 6*65536
  double* acc  = (double*)d_ws;       // 108 doubles

  hipMemsetAsync((void*)(out + NELEM), 0, (size_t)(1 + 6 * VOCAB) * sizeof(float), stream);
  hipMemsetAsync(d_ws, 0, 1024, stream);

  lfq_all<<<256, 1024, 0, stream>>>(f, phi_w, phi_b, fhi, hist, acc);
  finalize_total<<<1, 64, 0, stream>>>(acc, total);
}

// Round 8
// 370.877 us; speedup vs baseline: 1.0801x; 1.0801x over previous
//
#include <hip/hip_runtime.h>

#define VOCAB 65536
#define NELEM 4194304      // 256*16*32*32
#define BHW   262144       // 256*1024

__device__ __forceinline__ double cubic_d(double t) {
  const double a = -0.75;
  t = fabs(t);
  if (t <= 1.0) return ((a + 2.0) * t - (a + 3.0)) * t * t + 1.0;
  if (t < 2.0)  return a * (((t - 5.0) * t + 8.0) * t - 4.0);
  return 0.0;
}

// PN=32 idx slot: XOR swizzle -> conflict-free for writes (fixed y, varying x)
// and reads (fixed x, varying y). Bijective in (x,y).
__device__ __forceinline__ int idx32_slot(int x, int y) { return (x << 5) | ((y ^ x) & 31); }

// thread map (1024 threads): xq=t&7 (4-x strip, x0=4*xq), y=(t>>3)&31, g=t>>8
// owns channels 4g..4g+3. Persistent per-thread state = fhat[4][4] f64 ONLY.
template<int PN>
__device__ __forceinline__ void process_scale(
    int si, int phi_idx, bool load_w,
    const float* __restrict__ f, const float* __restrict__ phi_w,
    const float* __restrict__ phi_b, float* __restrict__ hist,
    double* __restrict__ acc, double (&fhat)[4][4],
    double* __restrict__ hupd, float* __restrict__ wlds,
    unsigned* __restrict__ idxL, float* __restrict__ wMT,
    float* __restrict__ bias16, double* __restrict__ red,
    int t, int y, int g, int x0, size_t ibase)
{
  constexpr int CELLS = PN * PN;
  constexpr int S = 32 / PN;
  const int w = t >> 6;   // wave id (16 waves)

  // ---------- P0: zero idx, (re)load weights, wM; stage resid + entropy/psum ----------
  idxL[t] = 0u;
  if (load_w) {
    for (int i = t; i < 2304; i += 1024) wlds[i] = phi_w[phi_idx * 2304 + i];
    if (t < 16) bias16[t] = phi_b[phi_idx * 16 + t];
  }
  if constexpr (PN != 32) {
    if (t < 32) {
      float wrow[PN];
      #pragma unroll
      for (int q = 0; q < PN; ++q) wrow[q] = 0.0f;
      double xp = ((double)t + 0.5) * (double)PN / 32.0 - 0.5;
      int q0 = (int)floor(xp);
      for (int k = 0; k < 4; ++k) {
        int j = q0 + k - 1;
        int jc = j < 0 ? 0 : (j > PN - 1 ? PN - 1 : j);
        wrow[jc] += (float)cubic_d(xp - (double)j);   // f32 accumulate == np M build
      }
      #pragma unroll
      for (int q = 0; q < PN; ++q) wMT[q * 32 + t] = wrow[q];
    }
    // stage resid AND compute entropy/psum from the in-register resid (1 f pass)
    float entf = 0.0f;
    float ps[4];
    #pragma unroll
    for (int cc = 0; cc < 4; ++cc) {
      const float4 fv = *(const float4*)(f + ibase + (size_t)(4 * g + cc) * 1024 + y * 32 + x0);
      double* hp = hupd + (4 * g + cc) * 1056 + y * 33 + x0;
      float psl = 0.0f;
      float fvk[4] = {fv.x, fv.y, fv.z, fv.w};
      #pragma unroll
      for (int k = 0; k < 4; ++k) {
        double xr = (double)fvk[k] - fhat[cc][k];
        hp[k] = xr;
        float pr = 1.0f / (1.0f + __expf(400.0f * (float)xr));   // sigmoid(-400 x)
        entf -= pr * __logf(pr + 1e-5f) + (1.0f - pr) * __logf(1.0f - pr + 1e-5f);
        psl += pr;
      }
      ps[cc] = psl;
    }
    double ent_d = (double)entf;
    #pragma unroll
    for (int off = 32; off > 0; off >>= 1) {
      ent_d += __shfl_down(ent_d, off);
      ps[0] += __shfl_down(ps[0], off);
      ps[1] += __shfl_down(ps[1], off);
      ps[2] += __shfl_down(ps[2], off);
      ps[3] += __shfl_down(ps[3], off);
    }
    if ((t & 63) == 0) {
      red[w * 6 + 1] = ent_d;
      red[w * 6 + 2] = (double)ps[0];
      red[w * 6 + 3] = (double)ps[1];
      red[w * 6 + 4] = (double)ps[2];
      red[w * 6 + 5] = (double)ps[3];
    }
  }
  __syncthreads();

  // ---------- P2: quantize (sign of f64 cell sums) -> idxL ----------
  if constexpr (PN == 32) {
    // resid from f directly; fuse entropy/psum here (pre-update resid)
    float entf = 0.0f;
    float ps[4];
    unsigned bb[4] = {0u, 0u, 0u, 0u};
    #pragma unroll
    for (int cc = 0; cc < 4; ++cc) {
      const float4 fv = *(const float4*)(f + ibase + (size_t)(4 * g + cc) * 1024 + y * 32 + x0);
      float psl = 0.0f;
      float fvk[4] = {fv.x, fv.y, fv.z, fv.w};
      #pragma unroll
      for (int k = 0; k < 4; ++k) {
        double xr = (double)fvk[k] - fhat[cc][k];
        if (xr > 0.0) bb[k] |= (1u << cc);
        float pr = 1.0f / (1.0f + __expf(400.0f * (float)xr));
        entf -= pr * __logf(pr + 1e-5f) + (1.0f - pr) * __logf(1.0f - pr + 1e-5f);
        psl += pr;
      }
      ps[cc] = psl;
    }
    #pragma unroll
    for (int k = 0; k < 4; ++k)
      if (bb[k]) atomicOr(&idxL[idx32_slot(x0 + k, y)], bb[k] << (4 * g));
    double ent_d = (double)entf;
    #pragma unroll
    for (int off = 32; off > 0; off >>= 1) {
      ent_d += __shfl_down(ent_d, off);
      ps[0] += __shfl_down(ps[0], off);
      ps[1] += __shfl_down(ps[1], off);
      ps[2] += __shfl_down(ps[2], off);
      ps[3] += __shfl_down(ps[3], off);
    }
    if ((t & 63) == 0) {
      red[w * 6 + 1] = ent_d;
      red[w * 6 + 2] = (double)ps[0];
      red[w * 6 + 3] = (double)ps[1];
      red[w * 6 + 4] = (double)ps[2];
      red[w * 6 + 5] = (double)ps[3];
    }
  } else if constexpr (PN == 16) {
    int cell = t & 255;
    int i0 = (cell >> 4) * 2, j0 = (cell & 15) * 2;
    unsigned bits = 0;
    #pragma unroll
    for (int k = 0; k < 4; ++k) {
      int c = (t >> 8) + 4 * k;
      const double* hp = hupd + c * 1056 + i0 * 33 + j0;
      double s = hp[0] + hp[1] + hp[33] + hp[34];
      if (s > 0.0) bits |= (1u << c);
    }
    atomicOr(&idxL[cell], bits);
  } else if constexpr (PN == 8) {
    int c = t >> 6, cell = t & 63;
    const double* hp = hupd + c * 1056 + ((cell >> 3) * 4) * 33 + (cell & 7) * 4;
    double s = 0.0;
    #pragma unroll
    for (int dy = 0; dy < 4; ++dy)
      #pragma unroll
      for (int dx = 0; dx < 4; ++dx) s += hp[dy * 33 + dx];
    if (s > 0.0) atomicOr(&idxL[cell], 1u << c);
  } else {   // PN 1,2,4
    constexpr int TASKS = 16 * CELLS;
    constexpr int G = 1024 / TASKS;       // 64, 16, 4
    int p = t / G, sub = t % G;
    int c = p / CELLS, cell = p % CELLS;
    const double* hp = hupd + c * 1056 + ((cell / PN) * S) * 33 + (cell % PN) * S;
    double s = 0.0;
    for (int e = sub; e < S * S; e += G) {
      int dy = e / S, dx = e % S;
      s += hp[dy * 33 + dx];
    }
    #pragma unroll
    for (int off = G / 2; off > 0; off >>= 1) s += __shfl_down(s, off, G);
    if (sub == 0 && s > 0.0) atomicOr(&idxL[cell], 1u << c);
  }
  __syncthreads();

  // ---------- P3: hist + upsample codes -> hupd (q-chunked, low reg pressure) ----------
  if constexpr (PN == 32) {
    atomicAdd(&hist[5 * VOCAB + idxL[t]], 1.0f);   // swizzle is bijective
  } else {
    if (t < CELLS) atomicAdd(&hist[(size_t)si * VOCAB + idxL[t]], 1.0f);
  }
  {
    int c2 = t >> 6, sub = (t >> 5) & 1, y2 = t & 31;
    double* hrow = hupd + c2 * 1056 + y2 * 33;
    if constexpr (PN == 32) {
      #pragma unroll
      for (int xi = 0; xi < 16; ++xi) {
        int x = 16 * sub + xi;
        hrow[x] = ((idxL[idx32_slot(x, y2)] >> c2) & 1) ? 1.0 : -1.0;
      }
    } else {
      constexpr int QC = (PN < 4) ? PN : 4;
      #pragma unroll
      for (int q0 = 0; q0 < PN; q0 += QC) {
        double tmp[QC];
        #pragma unroll
        for (int qq = 0; qq < QC; ++qq) tmp[qq] = 0.0;
        #pragma unroll
        for (int r = 0; r < PN; ++r) {
          double ww = (double)wMT[r * 32 + y2];
          #pragma unroll
          for (int qq = 0; qq < QC; ++qq) {
            double sg = ((idxL[r * PN + q0 + qq] >> c2) & 1) ? 1.0 : -1.0;
            tmp[qq] = fma(ww, sg, tmp[qq]);
          }
        }
        #pragma unroll
        for (int xi = 0; xi < 16; ++xi) {
          int x = 16 * sub + xi;
          double s2 = (q0 == 0) ? 0.0 : hrow[x];
          #pragma unroll
          for (int qq = 0; qq < QC; ++qq)
            s2 = fma((double)wMT[(q0 + qq) * 32 + x], tmp[qq], s2);
          hrow[x] = s2;
        }
      }
    }
  }
  __syncthreads();

  // ---------- P4: seed fhat, conv3x3 into fhat (0.5-scaled), mse ----------
  #pragma unroll
  for (int cc = 0; cc < 4; ++cc) {
    double bh = 0.5 * (double)bias16[4 * g + cc];
    const double* hu = hupd + (4 * g + cc) * 1056 + y * 33 + x0;
    #pragma unroll
    for (int k = 0; k < 4; ++k)
      fhat[cc][k] = fhat[cc][k] + 0.5 * hu[k] + bh;      // seed: 0.5*hup + 0.5*bias
  }

  for (int ci = 0; ci < 16; ++ci) {
    const double* hbase = hupd + ci * 1056;
    #pragma unroll
    for (int dy = 0; dy < 3; ++dy) {
      int ry = y + dy - 1;
      if (ry < 0 || ry > 31) continue;
      double prow[6];
      const double* hr = hbase + ry * 33;
      #pragma unroll
      for (int jj = 0; jj < 6; ++jj) {
        int xx = x0 - 1 + jj;
        prow[jj] = (xx < 0 || xx > 31) ? 0.0 : hr[xx];
      }
      #pragma unroll
      for (int cc = 0; cc < 4; ++cc) {
        const float* wp = wlds + (((4 * g + cc) * 16 + ci) * 9 + dy * 3);
        double w0 = 0.5 * (double)wp[0], w1 = 0.5 * (double)wp[1], w2 = 0.5 * (double)wp[2];
        #pragma unroll
        for (int k = 0; k < 4; ++k)
          fhat[cc][k] = fma(w0, prow[k], fma(w1, prow[k + 1], fma(w2, prow[k + 2], fhat[cc][k])));
      }
    }
  }

  double mse = 0.0;
  #pragma unroll
  for (int cc = 0; cc < 4; ++cc) {
    const float4 fv = *(const float4*)(f + ibase + (size_t)(4 * g + cc) * 1024 + y * 32 + x0);
    float fvk[4] = {fv.x, fv.y, fv.z, fv.w};
    #pragma unroll
    for (int k = 0; k < 4; ++k) {
      double d = fhat[cc][k] - (double)fvk[k];
      mse += d * d;
    }
  }
  #pragma unroll
  for (int off = 32; off > 0; off >>= 1) mse += __shfl_down(mse, off);
  if ((t & 63) == 0) red[w * 6 + 0] = mse;
  __syncthreads();

  // ---------- P5: block totals -> global acc ----------
  if (t == 0) {
    double m = 0.0, e = 0.0;
    #pragma unroll
    for (int ww = 0; ww < 16; ++ww) { m += red[ww * 6]; e += red[ww * 6 + 1]; }
    atomicAdd(&acc[si * 18 + 0], m);
    atomicAdd(&acc[si * 18 + 1], e);
  }
  if (t < 16) {
    int gg = t >> 2, cc = t & 3;
    double p = red[(4 * gg + 0) * 6 + 2 + cc] + red[(4 * gg + 1) * 6 + 2 + cc]
             + red[(4 * gg + 2) * 6 + 2 + cc] + red[(4 * gg + 3) * 6 + 2 + cc];
    atomicAdd(&acc[si * 18 + 2 + t], p);
  }
  __syncthreads();
}

__global__ __launch_bounds__(1024) void lfq_all(
    const float* __restrict__ f, const float* __restrict__ phi_w,
    const float* __restrict__ phi_b, float* __restrict__ fhi,
    float* __restrict__ hist, double* __restrict__ acc)
{
  __shared__ double   hupd[16 * 1056];   // 135168 B: resid / upsampled codes
  __shared__ float    wlds[2304];        // conv weights
  __shared__ unsigned idxL[1024];        // codes per cell (XOR-swizzled for PN=32)
  __shared__ float    wMT[512];          // bicubic M transposed [PN][32]
  __shared__ float    bias16[16];
  __shared__ double   red[96];           // 16 waves x 6 slots

  const int t = threadIdx.x;
  const int y = (t >> 3) & 31, g = t >> 8;
  const int x0 = (t & 7) * 4;
  const size_t ibase = (size_t)blockIdx.x * 16384;

  double fhat[4][4];
  #pragma unroll
  for (int cc = 0; cc < 4; ++cc)
    #pragma unroll
    for (int k = 0; k < 4; ++k) fhat[cc][k] = 0.0;

  // PHI_IDX = [0,0,1,2,3,3]
  process_scale<1 >(0, 0, true,  f, phi_w, phi_b, hist, acc, fhat, hupd, wlds, idxL, wMT, bias16, red, t, y, g, x0, ibase);
  process_scale<2 >(1, 0, false, f, phi_w, phi_b, hist, acc, fhat, hupd, wlds, idxL, wMT, bias16, red, t, y, g, x0, ibase);
  process_scale<4 >(2, 1, true,  f, phi_w, phi_b, hist, acc, fhat, hupd, wlds, idxL, wMT, bias16, red, t, y, g, x0, ibase);
  process_scale<8 >(3, 2, true,  f, phi_w, phi_b, hist, acc, fhat, hupd, wlds, idxL, wMT, bias16, red, t, y, g, x0, ibase);
  process_scale<16>(4, 3, true,  f, phi_w, phi_b, hist, acc, fhat, hupd, wlds, idxL, wMT, bias16, red, t, y, g, x0, ibase);
  process_scale<32>(5, 3, false, f, phi_w, phi_b, hist, acc, fhat, hupd, wlds, idxL, wMT, bias16, red, t, y, g, x0, ibase);

  #pragma unroll
  for (int cc = 0; cc < 4; ++cc) {
    float* op = fhi + ibase + (size_t)(4 * g + cc) * 1024 + y * 32 + x0;
    #pragma unroll
    for (int k = 0; k < 4; ++k) op[k] = (float)fhat[cc][k];
  }
}

__global__ void finalize_total(const double* __restrict__ acc, float* __restrict__ total)
{
  if (threadIdx.x == 0 && blockIdx.x == 0) {
    double vq = 0.0, ent = 0.0;
    for (int si = 0; si < 6; ++si) {
      vq += acc[si * 18 + 0];
      double pse = acc[si * 18 + 1] / (double)BHW;
      double ce = 0.0;
      for (int cc = 0; cc < 16; ++cc) {
        double ap0 = acc[si * 18 + 2 + cc] / (double)BHW;
        double ap1 = 1.0 - ap0;
        ce -= ap0 * log(ap0 + 1e-5) + ap1 * log(ap1 + 1e-5);
      }
      ent += pse - ce;
    }
    *total = (float)(1.25 * vq / ((double)NELEM * 6.0) + (0.1 / 6.0) * ent);
  }
}

extern "C" void kernel_launch(void* const* d_in, const int* in_sizes, int n_in,
                              void* d_out, int out_size, void* d_ws, size_t ws_size,
                              hipStream_t stream)
{
  const float* f     = (const float*)d_in[0];
  const float* phi_w = (const float*)d_in[1];
  const float* phi_b = (const float*)d_in[2];
  float* out   = (float*)d_out;
  float* fhi   = out;                 // [0, NELEM) — fully overwritten
  float* total = out + NELEM;
  float* hist  = out + NELEM + 1;     // 6*65536
  double* acc  = (double*)d_ws;       // 108 doubles

  hipMemsetAsync((void*)(out + NELEM), 0, (size_t)(1 + 6 * VOCAB) * sizeof(float), stream);
  hipMemsetAsync(d_ws, 0, 1024, stream);

  lfq_all<<<256, 1024, 0, stream>>>(f, phi_w, phi_b, fhi, hist, acc);
  finalize_total<<<1, 64, 0, stream>>>(acc, total);
}

// Round 9
// 309.347 us; speedup vs baseline: 1.2949x; 1.1989x over previous
//
#include <hip/hip_runtime.h>

#define VOCAB 65536
#define NELEM 4194304      // 256*16*32*32
#define BHW   262144       // 256*1024

__device__ __forceinline__ double cubic_d(double t) {
  const double a = -0.75;
  t = fabs(t);
  if (t <= 1.0) return ((a + 2.0) * t - (a + 3.0)) * t * t + 1.0;
  if (t < 2.0)  return a * (((t - 5.0) * t + 8.0) * t - 4.0);
  return 0.0;
}

// PN=32 idx slot: XOR swizzle, bijective, conflict-free both directions.
__device__ __forceinline__ int idx32_slot(int x, int y) { return (x << 5) | ((y ^ x) & 31); }

// 512 threads: xh=t&3 (8-x strip, x0=8*xh), y=(t>>2)&31, g=t>>7 owns ch 4g..4g+3.
// Persistent per-thread state: fhat[4][8] f64 (64 VGPR) under the 512-thr 128-VGPR budget.
template<int PN>
__device__ __forceinline__ void process_scale(
    int si, int phi_idx, bool load_w,
    const float* __restrict__ f, const float* __restrict__ phi_w,
    const float* __restrict__ phi_b, float* __restrict__ hist,
    double* __restrict__ acc, double (&fhat)[4][8],
    double* __restrict__ hupd, float* __restrict__ wlds,
    unsigned* __restrict__ idxL, float* __restrict__ wMT,
    float* __restrict__ bias16, double* __restrict__ red,
    int t, int y, int g, int x0, size_t ibase)
{
  constexpr int CELLS = PN * PN;
  constexpr int S = 32 / PN;
  const int w = t >> 6;   // 8 waves

  // ---------- P0: zero idx, weights, wM; stage resid + entropy/psum + PREV mse ----------
  idxL[t] = 0u; idxL[t + 512] = 0u;
  if (load_w) {
    for (int i = t; i < 2304; i += 512) wlds[i] = phi_w[phi_idx * 2304 + i];
    if (t < 16) bias16[t] = phi_b[phi_idx * 16 + t];
  }
  if constexpr (PN != 32) {
    if (t < 32) {
      #pragma unroll
      for (int q = 0; q < PN; ++q) wMT[q * 32 + t] = 0.0f;
      double xp = ((double)t + 0.5) * (double)PN / 32.0 - 0.5;
      int q0i = (int)floor(xp);
      for (int k = 0; k < 4; ++k) {
        int j = q0i + k - 1;
        int jc = j < 0 ? 0 : (j > PN - 1 ? PN - 1 : j);
        wMT[jc * 32 + t] += (float)cubic_d(xp - (double)j);   // f32 accumulate == np M build
      }
    }
    double mseP = 0.0;
    float entf = 0.0f, ps0 = 0, ps1 = 0, ps2 = 0, ps3 = 0;
    #pragma unroll
    for (int cc = 0; cc < 4; ++cc) {
      const float* fp = f + ibase + (size_t)(4 * g + cc) * 1024 + y * 32 + x0;
      float4 fa = *(const float4*)fp;
      float4 fb = *(const float4*)(fp + 4);
      float fvk[8] = {fa.x, fa.y, fa.z, fa.w, fb.x, fb.y, fb.z, fb.w};
      double* hp = hupd + (4 * g + cc) * 1056 + y * 33 + x0;
      float psl = 0.0f;
      #pragma unroll
      for (int k = 0; k < 8; ++k) {
        double xr = (double)fvk[k] - fhat[cc][k];
        hp[k] = xr;
        mseP += xr * xr;                                  // == prev scale's mse term
        float pr = 1.0f / (1.0f + __expf(400.0f * (float)xr));   // sigmoid(-400 x)
        entf -= pr * __logf(pr + 1e-5f) + (1.0f - pr) * __logf(1.0f - pr + 1e-5f);
        psl += pr;
      }
      if (cc == 0) ps0 = psl; else if (cc == 1) ps1 = psl; else if (cc == 2) ps2 = psl; else ps3 = psl;
    }
    double ent_d = (double)entf;
    #pragma unroll
    for (int off = 32; off > 0; off >>= 1) {
      mseP  += __shfl_down(mseP, off);
      ent_d += __shfl_down(ent_d, off);
      ps0 += __shfl_down(ps0, off); ps1 += __shfl_down(ps1, off);
      ps2 += __shfl_down(ps2, off); ps3 += __shfl_down(ps3, off);
    }
    if ((t & 63) == 0) {
      red[w * 8 + 0] = mseP; red[w * 8 + 1] = ent_d;
      red[w * 8 + 2] = (double)ps0; red[w * 8 + 3] = (double)ps1;
      red[w * 8 + 4] = (double)ps2; red[w * 8 + 5] = (double)ps3;
    }
  }
  __syncthreads();

  if constexpr (PN != 32) {   // flush block reductions (reads red)
    if (t == 0) {
      double m = 0.0, e = 0.0;
      #pragma unroll
      for (int ww = 0; ww < 8; ++ww) { m += red[ww * 8]; e += red[ww * 8 + 1]; }
      if (si > 0) atomicAdd(&acc[(si - 1) * 18 + 0], m);
      atomicAdd(&acc[si * 18 + 1], e);
    }
    if (t < 16) {
      int gg = t >> 2, cc = t & 3;   // channel t owned by waves 2gg, 2gg+1
      atomicAdd(&acc[si * 18 + 2 + t], red[(2 * gg) * 8 + 2 + cc] + red[(2 * gg + 1) * 8 + 2 + cc]);
    }
  }

  // ---------- P2: quantize (sign of f64 cell sums) ----------
  if constexpr (PN == 32) {
    // fused: signs + entropy/psum + scale-4 mse (pre-update resid)
    double mseP = 0.0;
    float entf = 0.0f, ps0 = 0, ps1 = 0, ps2 = 0, ps3 = 0;
    unsigned bb[8] = {0, 0, 0, 0, 0, 0, 0, 0};
    #pragma unroll
    for (int cc = 0; cc < 4; ++cc) {
      const float* fp = f + ibase + (size_t)(4 * g + cc) * 1024 + y * 32 + x0;
      float4 fa = *(const float4*)fp;
      float4 fb = *(const float4*)(fp + 4);
      float fvk[8] = {fa.x, fa.y, fa.z, fa.w, fb.x, fb.y, fb.z, fb.w};
      float psl = 0.0f;
      #pragma unroll
      for (int k = 0; k < 8; ++k) {
        double xr = (double)fvk[k] - fhat[cc][k];
        if (xr > 0.0) bb[k] |= (1u << cc);
        mseP += xr * xr;
        float pr = 1.0f / (1.0f + __expf(400.0f * (float)xr));
        entf -= pr * __logf(pr + 1e-5f) + (1.0f - pr) * __logf(1.0f - pr + 1e-5f);
        psl += pr;
      }
      if (cc == 0) ps0 = psl; else if (cc == 1) ps1 = psl; else if (cc == 2) ps2 = psl; else ps3 = psl;
    }
    #pragma unroll
    for (int k = 0; k < 8; ++k)
      if (bb[k]) atomicOr(&idxL[idx32_slot(x0 + k, y)], bb[k] << (4 * g));
    double ent_d = (double)entf;
    #pragma unroll
    for (int off = 32; off > 0; off >>= 1) {
      mseP  += __shfl_down(mseP, off);
      ent_d += __shfl_down(ent_d, off);
      ps0 += __shfl_down(ps0, off); ps1 += __shfl_down(ps1, off);
      ps2 += __shfl_down(ps2, off); ps3 += __shfl_down(ps3, off);
    }
    if ((t & 63) == 0) {
      red[w * 8 + 0] = mseP; red[w * 8 + 1] = ent_d;
      red[w * 8 + 2] = (double)ps0; red[w * 8 + 3] = (double)ps1;
      red[w * 8 + 4] = (double)ps2; red[w * 8 + 5] = (double)ps3;
    }
  } else if constexpr (PN == 16) {
    int cell = t & 255;
    int i0 = (cell >> 4) * 2, j0 = (cell & 15) * 2;
    unsigned bits = 0;
    #pragma unroll
    for (int k = 0; k < 8; ++k) {
      int c = (t >> 8) + 2 * k;
      const double* hp = hupd + c * 1056 + i0 * 33 + j0;
      double s = hp[0] + hp[1] + hp[33] + hp[34];
      if (s > 0.0) bits |= (1u << c);
    }
    atomicOr(&idxL[cell], bits);
  } else if constexpr (PN == 8) {
    #pragma unroll
    for (int k = 0; k < 2; ++k) {
      int task = t + 512 * k;
      int c = task >> 6, cell = task & 63;
      const double* hp = hupd + c * 1056 + ((cell >> 3) * 4) * 33 + (cell & 7) * 4;
      double s = 0.0;
      #pragma unroll
      for (int dy = 0; dy < 4; ++dy)
        #pragma unroll
        for (int dx = 0; dx < 4; ++dx) s += hp[dy * 33 + dx];
      if (s > 0.0) atomicOr(&idxL[cell], 1u << c);
    }
  } else {   // PN 1,2,4
    constexpr int TASKS = 16 * CELLS;     // 16, 64, 256
    constexpr int G = 512 / TASKS;        // 32, 8, 2
    int p = t / G, sub = t % G;
    int c = p / CELLS, cell = p % CELLS;
    const double* hp = hupd + c * 1056 + ((cell / PN) * S) * 33 + (cell % PN) * S;
    double s = 0.0;
    for (int e = sub; e < S * S; e += G) s += hp[(e / S) * 33 + (e % S)];
    #pragma unroll
    for (int off = G / 2; off > 0; off >>= 1) s += __shfl_down(s, off, G);
    if (sub == 0 && s > 0.0) atomicOr(&idxL[cell], 1u << c);
  }
  __syncthreads();

  if constexpr (PN == 32) {   // flush scale-4 mse + scale-5 ent/ps
    if (t == 0) {
      double m = 0.0, e = 0.0;
      #pragma unroll
      for (int ww = 0; ww < 8; ++ww) { m += red[ww * 8]; e += red[ww * 8 + 1]; }
      atomicAdd(&acc[4 * 18 + 0], m);
      atomicAdd(&acc[5 * 18 + 1], e);
    }
    if (t < 16) {
      int gg = t >> 2, cc = t & 3;
      atomicAdd(&acc[5 * 18 + 2 + t], red[(2 * gg) * 8 + 2 + cc] + red[(2 * gg + 1) * 8 + 2 + cc]);
    }
  }

  // ---------- P3: hist + upsample codes -> hupd ----------
  if constexpr (PN == 32) {
    atomicAdd(&hist[5 * VOCAB + idxL[t]], 1.0f);         // swizzle bijective
    atomicAdd(&hist[5 * VOCAB + idxL[t + 512]], 1.0f);
  } else {
    if (t < CELLS) atomicAdd(&hist[(size_t)si * VOCAB + idxL[t]], 1.0f);
  }
  {
    int c2 = t >> 5, y2 = t & 31;
    double* hrow = hupd + c2 * 1056 + y2 * 33;
    if constexpr (PN == 32) {
      #pragma unroll
      for (int x = 0; x < 32; ++x)
        hrow[x] = ((idxL[idx32_slot(x, y2)] >> c2) & 1) ? 1.0 : -1.0;
    } else {
      constexpr int QC = (PN < 4) ? PN : 4;
      #pragma unroll
      for (int q0 = 0; q0 < PN; q0 += QC) {
        double tmp[QC];
        #pragma unroll
        for (int qq = 0; qq < QC; ++qq) tmp[qq] = 0.0;
        #pragma unroll
        for (int r = 0; r < PN; ++r) {
          double ww = (double)wMT[r * 32 + y2];
          #pragma unroll
          for (int qq = 0; qq < QC; ++qq) {
            double sg = ((idxL[r * PN + q0 + qq] >> c2) & 1) ? 1.0 : -1.0;
            tmp[qq] = fma(ww, sg, tmp[qq]);
          }
        }
        #pragma unroll
        for (int x = 0; x < 32; ++x) {
          double s2 = (q0 == 0) ? 0.0 : hrow[x];
          #pragma unroll
          for (int qq = 0; qq < QC; ++qq)
            s2 = fma((double)wMT[(q0 + qq) * 32 + x], tmp[qq], s2);
          hrow[x] = s2;
        }
      }
    }
  }
  __syncthreads();

  // ---------- P4: seed fhat, conv3x3 into fhat (0.5-scaled weights) ----------
  #pragma unroll
  for (int cc = 0; cc < 4; ++cc) {
    double bh = 0.5 * (double)bias16[4 * g + cc];
    const double* hu = hupd + (4 * g + cc) * 1056 + y * 33 + x0;
    #pragma unroll
    for (int k = 0; k < 8; ++k)
      fhat[cc][k] = fhat[cc][k] + 0.5 * hu[k] + bh;
  }
  for (int ci = 0; ci < 16; ++ci) {
    const double* hbase = hupd + ci * 1056;
    #pragma unroll
    for (int dy = 0; dy < 3; ++dy) {
      int ry = y + dy - 1;
      if (ry < 0 || ry > 31) continue;
      double prow[10];
      const double* hr = hbase + ry * 33;
      #pragma unroll
      for (int jj = 0; jj < 10; ++jj) {
        int xx = x0 - 1 + jj;
        prow[jj] = (xx < 0 || xx > 31) ? 0.0 : hr[xx];
      }
      #pragma unroll
      for (int cc = 0; cc < 4; ++cc) {
        const float* wp = wlds + (((4 * g + cc) * 16 + ci) * 9 + dy * 3);
        double w0 = 0.5 * (double)wp[0], w1 = 0.5 * (double)wp[1], w2 = 0.5 * (double)wp[2];
        #pragma unroll
        for (int k = 0; k < 8; ++k)
          fhat[cc][k] = fma(w0, prow[k], fma(w1, prow[k + 1], fma(w2, prow[k + 2], fhat[cc][k])));
      }
    }
  }
  __syncthreads();
}

__global__ __launch_bounds__(512) void lfq_all(
    const float* __restrict__ f, const float* __restrict__ phi_w,
    const float* __restrict__ phi_b, float* __restrict__ fhi,
    float* __restrict__ hist, double* __restrict__ acc)
{
  __shared__ double   hupd[16 * 1056];   // 135168 B
  __shared__ float    wlds[2304];
  __shared__ unsigned idxL[1024];
  __shared__ float    wMT[512];          // bicubic M transposed [PN][32]
  __shared__ float    bias16[16];
  __shared__ double   red[64];           // 8 waves x 8 slots

  const int t = threadIdx.x;
  const int y = (t >> 2) & 31, g = t >> 7;
  const int x0 = (t & 3) * 8;
  const size_t ibase = (size_t)blockIdx.x * 16384;
  const int w = t >> 6;

  double fhat[4][8];
  #pragma unroll
  for (int cc = 0; cc < 4; ++cc)
    #pragma unroll
    for (int k = 0; k < 8; ++k) fhat[cc][k] = 0.0;

  // PHI_IDX = [0,0,1,2,3,3]
  process_scale<1 >(0, 0, true,  f, phi_w, phi_b, hist, acc, fhat, hupd, wlds, idxL, wMT, bias16, red, t, y, g, x0, ibase);
  process_scale<2 >(1, 0, false, f, phi_w, phi_b, hist, acc, fhat, hupd, wlds, idxL, wMT, bias16, red, t, y, g, x0, ibase);
  process_scale<4 >(2, 1, true,  f, phi_w, phi_b, hist, acc, fhat, hupd, wlds, idxL, wMT, bias16, red, t, y, g, x0, ibase);
  process_scale<8 >(3, 2, true,  f, phi_w, phi_b, hist, acc, fhat, hupd, wlds, idxL, wMT, bias16, red, t, y, g, x0, ibase);
  process_scale<16>(4, 3, true,  f, phi_w, phi_b, hist, acc, fhat, hupd, wlds, idxL, wMT, bias16, red, t, y, g, x0, ibase);
  process_scale<32>(5, 3, false, f, phi_w, phi_b, hist, acc, fhat, hupd, wlds, idxL, wMT, bias16, red, t, y, g, x0, ibase);

  // final (scale 6) mse
  double mse = 0.0;
  #pragma unroll
  for (int cc = 0; cc < 4; ++cc) {
    const float* fp = f + ibase + (size_t)(4 * g + cc) * 1024 + y * 32 + x0;
    float4 fa = *(const float4*)fp;
    float4 fb = *(const float4*)(fp + 4);
    float fvk[8] = {fa.x, fa.y, fa.z, fa.w, fb.x, fb.y, fb.z, fb.w};
    #pragma unroll
    for (int k = 0; k < 8; ++k) {
      double d = fhat[cc][k] - (double)fvk[k];
      mse += d * d;
    }
  }
  #pragma unroll
  for (int off = 32; off > 0; off >>= 1) mse += __shfl_down(mse, off);
  if ((t & 63) == 0) red[w * 8] = mse;
  __syncthreads();
  if (t == 0) {
    double m = 0.0;
    #pragma unroll
    for (int ww = 0; ww < 8; ++ww) m += red[ww * 8];
    atomicAdd(&acc[5 * 18 + 0], m);
  }

  // output
  #pragma unroll
  for (int cc = 0; cc < 4; ++cc) {
    float* op = fhi + ibase + (size_t)(4 * g + cc) * 1024 + y * 32 + x0;
    float4 o1 = make_float4((float)fhat[cc][0], (float)fhat[cc][1], (float)fhat[cc][2], (float)fhat[cc][3]);
    float4 o2 = make_float4((float)fhat[cc][4], (float)fhat[cc][5], (float)fhat[cc][6], (float)fhat[cc][7]);
    *(float4*)op = o1;
    *(float4*)(op + 4) = o2;
  }
}

__global__ void finalize_total(const double* __restrict__ acc, float* __restrict__ total)
{
  if (threadIdx.x == 0 && blockIdx.x == 0) {
    double vq = 0.0, ent = 0.0;
    for (int si = 0; si < 6; ++si) {
      vq += acc[si * 18 + 0];
      double pse = acc[si * 18 + 1] / (double)BHW;
      double ce = 0.0;
      for (int cc = 0; cc < 16; ++cc) {
        double ap0 = acc[si * 18 + 2 + cc] / (double)BHW;
        double ap1 = 1.0 - ap0;
        ce -= ap0 * log(ap0 + 1e-5) + ap1 * log(ap1 + 1e-5);
      }
      ent += pse - ce;
    }
    *total = (float)(1.25 * vq / ((double)NELEM * 6.0) + (0.1 / 6.0) * ent);
  }
}

extern "C" void kernel_launch(void* const* d_in, const int* in_sizes, int n_in,
                              void* d_out, int out_size, void* d_ws, size_t ws_size,
                              hipStream_t stream)
{
  const float* f     = (const float*)d_in[0];
  const float* phi_w = (const float*)d_in[1];
  const float* phi_b = (const float*)d_in[2];
  float* out   = (float*)d_out;
  float* fhi   = out;                 // fully overwritten
  float* total = out + NELEM;
  float* hist  = out + NELEM + 1;     // 6*65536
  double* acc  = (double*)d_ws;       // 108 doubles

  hipMemsetAsync((void*)(out + NELEM), 0, (size_t)(1 + 6 * VOCAB) * sizeof(float), stream);
  hipMemsetAsync(d_ws, 0, 1024, stream);

  lfq_all<<<256, 512, 0, stream>>>(f, phi_w, phi_b, fhi, hist, acc);
  finalize_total<<<1, 64, 0, stream>>>(acc, total);
}

// Round 11
// 303.483 us; speedup vs baseline: 1.3199x; 1.0193x over previous
//
#include <hip/hip_runtime.h>

#define VOCAB 65536
#define NELEM 4194304      // 256*16*32*32
#define BHW   262144       // 256*1024

__device__ __forceinline__ double cubic_d(double t) {
  const double a = -0.75;
  t = fabs(t);
  if (t <= 1.0) return ((a + 2.0) * t - (a + 3.0)) * t * t + 1.0;
  if (t < 2.0)  return a * (((t - 5.0) * t + 8.0) * t - 4.0);
  return 0.0;
}

// PN=32 idx slot: XOR swizzle, bijective, conflict-free both directions.
__device__ __forceinline__ int idx32_slot(int x, int y) { return (x << 5) | ((y ^ x) & 31); }

// 512 threads: x0=(t&3)*8, y=(t>>2)&31, g=t>>7 (wave-uniform, SGPR) owns ch 4g..4g+3.
// Entire h chain is f64 (bit-identical to the passing r9 kernel). fown = f in regs.
template<int PN>
__device__ __forceinline__ void process_scale(
    int si, int phi_idx,
    const float* __restrict__ phi_w, const float* __restrict__ phi_b,
    float* __restrict__ hist, double* __restrict__ acc,
    const float (&fown)[4][8], double (&fhat)[4][8],
    double* __restrict__ hupd, unsigned* __restrict__ idxL,
    float* __restrict__ wMT, double* __restrict__ red,
    int t, int y, int g, int x0)
{
  constexpr int CELLS = PN * PN;
  constexpr int S = 32 / PN;
  const int w = t >> 6;   // 8 waves

  // ---------- P0: zero idx, wM; stage resid + entropy/psum + PREV mse ----------
  idxL[t] = 0u; idxL[t + 512] = 0u;
  if constexpr (PN != 32) {
    if (t < 32) {
      #pragma unroll
      for (int q = 0; q < PN; ++q) wMT[q * 32 + t] = 0.0f;
      double xp = ((double)t + 0.5) * (double)PN / 32.0 - 0.5;
      int q0i = (int)floor(xp);
      for (int k = 0; k < 4; ++k) {
        int j = q0i + k - 1;
        int jc = j < 0 ? 0 : (j > PN - 1 ? PN - 1 : j);
        wMT[jc * 32 + t] += (float)cubic_d(xp - (double)j);   // f32 accumulate == np M build
      }
    }
    double mseP = 0.0;
    float entf = 0.0f, ps0 = 0, ps1 = 0, ps2 = 0, ps3 = 0;
    #pragma unroll
    for (int cc = 0; cc < 4; ++cc) {
      double* hp = hupd + (4 * g + cc) * 1056 + y * 33 + x0;
      float psl = 0.0f;
      #pragma unroll
      for (int k = 0; k < 8; ++k) {
        double xr = (double)fown[cc][k] - fhat[cc][k];
        hp[k] = xr;
        mseP += xr * xr;                                  // prev scale's mse term
        float pr = 1.0f / (1.0f + __expf(400.0f * (float)xr));   // sigmoid(-400 x)
        entf -= pr * __logf(pr + 1e-5f) + (1.0f - pr) * __logf(1.0f - pr + 1e-5f);
        psl += pr;
      }
      if (cc == 0) ps0 = psl; else if (cc == 1) ps1 = psl; else if (cc == 2) ps2 = psl; else ps3 = psl;
    }
    double ent_d = (double)entf;
    #pragma unroll
    for (int off = 32; off > 0; off >>= 1) {
      mseP  += __shfl_down(mseP, off);
      ent_d += __shfl_down(ent_d, off);
      ps0 += __shfl_down(ps0, off); ps1 += __shfl_down(ps1, off);
      ps2 += __shfl_down(ps2, off); ps3 += __shfl_down(ps3, off);
    }
    if ((t & 63) == 0) {
      red[w * 8 + 0] = mseP; red[w * 8 + 1] = ent_d;
      red[w * 8 + 2] = (double)ps0; red[w * 8 + 3] = (double)ps1;
      red[w * 8 + 4] = (double)ps2; red[w * 8 + 5] = (double)ps3;
    }
  }
  __syncthreads();

  if constexpr (PN != 32) {   // flush block reductions
    if (t == 0) {
      double m = 0.0, e = 0.0;
      #pragma unroll
      for (int ww = 0; ww < 8; ++ww) { m += red[ww * 8]; e += red[ww * 8 + 1]; }
      if (si > 0) atomicAdd(&acc[(si - 1) * 18 + 0], m);
      atomicAdd(&acc[si * 18 + 1], e);
    }
    if (t < 16) {
      int gg = t >> 2, cc = t & 3;
      atomicAdd(&acc[si * 18 + 2 + t], red[(2 * gg) * 8 + 2 + cc] + red[(2 * gg + 1) * 8 + 2 + cc]);
    }
  }

  // ---------- P2: quantize (sign of f64 cell sums) ----------
  if constexpr (PN == 32) {
    double mseP = 0.0;
    float entf = 0.0f, ps0 = 0, ps1 = 0, ps2 = 0, ps3 = 0;
    unsigned bb[8] = {0, 0, 0, 0, 0, 0, 0, 0};
    #pragma unroll
    for (int cc = 0; cc < 4; ++cc) {
      float psl = 0.0f;
      #pragma unroll
      for (int k = 0; k < 8; ++k) {
        double xr = (double)fown[cc][k] - fhat[cc][k];
        if (xr > 0.0) bb[k] |= (1u << cc);
        mseP += xr * xr;
        float pr = 1.0f / (1.0f + __expf(400.0f * (float)xr));
        entf -= pr * __logf(pr + 1e-5f) + (1.0f - pr) * __logf(1.0f - pr + 1e-5f);
        psl += pr;
      }
      if (cc == 0) ps0 = psl; else if (cc == 1) ps1 = psl; else if (cc == 2) ps2 = psl; else ps3 = psl;
    }
    #pragma unroll
    for (int k = 0; k < 8; ++k)
      if (bb[k]) atomicOr(&idxL[idx32_slot(x0 + k, y)], bb[k] << (4 * g));
    double ent_d = (double)entf;
    #pragma unroll
    for (int off = 32; off > 0; off >>= 1) {
      mseP  += __shfl_down(mseP, off);
      ent_d += __shfl_down(ent_d, off);
      ps0 += __shfl_down(ps0, off); ps1 += __shfl_down(ps1, off);
      ps2 += __shfl_down(ps2, off); ps3 += __shfl_down(ps3, off);
    }
    if ((t & 63) == 0) {
      red[w * 8 + 0] = mseP; red[w * 8 + 1] = ent_d;
      red[w * 8 + 2] = (double)ps0; red[w * 8 + 3] = (double)ps1;
      red[w * 8 + 4] = (double)ps2; red[w * 8 + 5] = (double)ps3;
    }
  } else if constexpr (PN == 16) {
    int cell = t & 255;
    int i0 = (cell >> 4) * 2, j0 = (cell & 15) * 2;
    unsigned bits = 0;
    #pragma unroll
    for (int k = 0; k < 8; ++k) {
      int c = (t >> 8) + 2 * k;
      const double* hp = hupd + c * 1056 + i0 * 33 + j0;
      double s = hp[0] + hp[1] + hp[33] + hp[34];
      if (s > 0.0) bits |= (1u << c);
    }
    atomicOr(&idxL[cell], bits);
  } else if constexpr (PN == 8) {
    #pragma unroll
    for (int k = 0; k < 2; ++k) {
      int task = t + 512 * k;
      int c = task >> 6, cell = task & 63;
      const double* hp = hupd + c * 1056 + ((cell >> 3) * 4) * 33 + (cell & 7) * 4;
      double s = 0.0;
      #pragma unroll
      for (int dy = 0; dy < 4; ++dy)
        #pragma unroll
        for (int dx = 0; dx < 4; ++dx) s += hp[dy * 33 + dx];
      if (s > 0.0) atomicOr(&idxL[cell], 1u << c);
    }
  } else {   // PN 1,2,4
    constexpr int TASKS = 16 * CELLS;     // 16, 64, 256
    constexpr int G = 512 / TASKS;        // 32, 8, 2
    int p = t / G, sub = t % G;
    int c = p / CELLS, cell = p % CELLS;
    const double* hp = hupd + c * 1056 + ((cell / PN) * S) * 33 + (cell % PN) * S;
    double s = 0.0;
    for (int e = sub; e < S * S; e += G) s += hp[(e / S) * 33 + (e % S)];
    #pragma unroll
    for (int off = G / 2; off > 0; off >>= 1) s += __shfl_down(s, off, G);
    if (sub == 0 && s > 0.0) atomicOr(&idxL[cell], 1u << c);
  }
  __syncthreads();

  if constexpr (PN == 32) {   // flush scale-4 mse + scale-5 ent/ps
    if (t == 0) {
      double m = 0.0, e = 0.0;
      #pragma unroll
      for (int ww = 0; ww < 8; ++ww) { m += red[ww * 8]; e += red[ww * 8 + 1]; }
      atomicAdd(&acc[4 * 18 + 0], m);
      atomicAdd(&acc[5 * 18 + 1], e);
    }
    if (t < 16) {
      int gg = t >> 2, cc = t & 3;
      atomicAdd(&acc[5 * 18 + 2 + t], red[(2 * gg) * 8 + 2 + cc] + red[(2 * gg + 1) * 8 + 2 + cc]);
    }
  }

  // ---------- P3: hist + upsample codes -> hupd ----------
  if constexpr (PN == 32) {
    atomicAdd(&hist[5 * VOCAB + idxL[t]], 1.0f);         // swizzle bijective
    atomicAdd(&hist[5 * VOCAB + idxL[t + 512]], 1.0f);
  } else {
    if (t < CELLS) atomicAdd(&hist[(size_t)si * VOCAB + idxL[t]], 1.0f);
  }
  {
    int c2 = t >> 5, y2 = t & 31;
    double* hrow = hupd + c2 * 1056 + y2 * 33;
    if constexpr (PN == 32) {
      #pragma unroll
      for (int x = 0; x < 32; ++x)
        hrow[x] = ((idxL[idx32_slot(x, y2)] >> c2) & 1) ? 1.0 : -1.0;
    } else {
      constexpr int QC = (PN < 4) ? PN : 4;
      #pragma unroll
      for (int q0 = 0; q0 < PN; q0 += QC) {
        double tmp[QC];
        #pragma unroll
        for (int qq = 0; qq < QC; ++qq) tmp[qq] = 0.0;
        #pragma unroll
        for (int r = 0; r < PN; ++r) {
          double ww = (double)wMT[r * 32 + y2];
          #pragma unroll
          for (int qq = 0; qq < QC; ++qq) {
            double sg = ((idxL[r * PN + q0 + qq] >> c2) & 1) ? 1.0 : -1.0;
            tmp[qq] = fma(ww, sg, tmp[qq]);
          }
        }
        #pragma unroll
        for (int x = 0; x < 32; ++x) {
          double s2 = (q0 == 0) ? 0.0 : hrow[x];
          #pragma unroll
          for (int qq = 0; qq < QC; ++qq)
            s2 = fma((double)wMT[(q0 + qq) * 32 + x], tmp[qq], s2);
          hrow[x] = s2;
        }
      }
    }
  }
  __syncthreads();

  // ---------- P4: seed fhat, conv3x3 into fhat (0.5-scaled weights from SGPR) ----------
  const float* wgbase = phi_w + phi_idx * 2304;   // wave-uniform -> scalar loads
  #pragma unroll
  for (int cc = 0; cc < 4; ++cc) {
    double bh = 0.5 * (double)phi_b[phi_idx * 16 + 4 * g + cc];
    const double* hu = hupd + (4 * g + cc) * 1056 + y * 33 + x0;
    #pragma unroll
    for (int k = 0; k < 8; ++k)
      fhat[cc][k] = fhat[cc][k] + 0.5 * hu[k] + bh;
  }
  for (int ci = 0; ci < 16; ++ci) {
    const double* hbase = hupd + ci * 1056;
    #pragma unroll
    for (int dy = 0; dy < 3; ++dy) {
      int ry = y + dy - 1;
      if (ry < 0 || ry > 31) continue;
      double prow[10];
      const double* hr = hbase + ry * 33;
      // interior taps are statically in-range; only the two halo taps need selects
      prow[0] = (x0 == 0)  ? 0.0 : hr[x0 - 1];
      #pragma unroll
      for (int jj = 1; jj < 9; ++jj) prow[jj] = hr[x0 - 1 + jj];
      prow[9] = (x0 == 24) ? 0.0 : hr[x0 + 8];
      #pragma unroll
      for (int cc = 0; cc < 4; ++cc) {
        const float* wp = wgbase + ((4 * g + cc) * 16 + ci) * 9 + dy * 3;  // SGPR addr
        double w0 = 0.5 * (double)wp[0], w1 = 0.5 * (double)wp[1], w2 = 0.5 * (double)wp[2];
        #pragma unroll
        for (int k = 0; k < 8; ++k)
          fhat[cc][k] = fma(w0, prow[k], fma(w1, prow[k + 1], fma(w2, prow[k + 2], fhat[cc][k])));
      }
    }
  }
  __syncthreads();
}

__global__ __launch_bounds__(512) void lfq_all(
    const float* __restrict__ f, const float* __restrict__ phi_w,
    const float* __restrict__ phi_b, float* __restrict__ fhi,
    float* __restrict__ hist, double* __restrict__ acc)
{
  __shared__ double   hupd[16 * 1056];   // 135168 B
  __shared__ unsigned idxL[1024];
  __shared__ float    wMT[512];          // bicubic M transposed [PN][32]
  __shared__ double   red[64];           // 8 waves x 8 slots

  const int t = threadIdx.x;
  const int y = (t >> 2) & 31;
  const int x0 = (t & 3) * 8;
  const int g = __builtin_amdgcn_readfirstlane(t >> 7);   // wave-uniform -> SGPR
  const size_t ibase = (size_t)blockIdx.x * 16384;
  const int w = t >> 6;

  float fown[4][8];
  double fhat[4][8];
  #pragma unroll
  for (int cc = 0; cc < 4; ++cc) {
    const float* fp = f + ibase + (size_t)(4 * g + cc) * 1024 + y * 32 + x0;
    float4 fa = *(const float4*)fp;
    float4 fb = *(const float4*)(fp + 4);
    fown[cc][0] = fa.x; fown[cc][1] = fa.y; fown[cc][2] = fa.z; fown[cc][3] = fa.w;
    fown[cc][4] = fb.x; fown[cc][5] = fb.y; fown[cc][6] = fb.z; fown[cc][7] = fb.w;
    #pragma unroll
    for (int k = 0; k < 8; ++k) fhat[cc][k] = 0.0;
  }

  // PHI_IDX = [0,0,1,2,3,3]
  process_scale<1 >(0, 0, phi_w, phi_b, hist, acc, fown, fhat, hupd, idxL, wMT, red, t, y, g, x0);
  process_scale<2 >(1, 0, phi_w, phi_b, hist, acc, fown, fhat, hupd, idxL, wMT, red, t, y, g, x0);
  process_scale<4 >(2, 1, phi_w, phi_b, hist, acc, fown, fhat, hupd, idxL, wMT, red, t, y, g, x0);
  process_scale<8 >(3, 2, phi_w, phi_b, hist, acc, fown, fhat, hupd, idxL, wMT, red, t, y, g, x0);
  process_scale<16>(4, 3, phi_w, phi_b, hist, acc, fown, fhat, hupd, idxL, wMT, red, t, y, g, x0);
  process_scale<32>(5, 3, phi_w, phi_b, hist, acc, fown, fhat, hupd, idxL, wMT, red, t, y, g, x0);

  // final (scale 6) mse
  double mse = 0.0;
  #pragma unroll
  for (int cc = 0; cc < 4; ++cc)
    #pragma unroll
    for (int k = 0; k < 8; ++k) {
      double d = fhat[cc][k] - (double)fown[cc][k];
      mse += d * d;
    }
  #pragma unroll
  for (int off = 32; off > 0; off >>= 1) mse += __shfl_down(mse, off);
  if ((t & 63) == 0) red[w * 8] = mse;
  __syncthreads();
  if (t == 0) {
    double m = 0.0;
    #pragma unroll
    for (int ww = 0; ww < 8; ++ww) m += red[ww * 8];
    atomicAdd(&acc[5 * 18 + 0], m);
  }

  // output
  #pragma unroll
  for (int cc = 0; cc < 4; ++cc) {
    float* op = fhi + ibase + (size_t)(4 * g + cc) * 1024 + y * 32 + x0;
    *(float4*)op = make_float4((float)fhat[cc][0], (float)fhat[cc][1],
                               (float)fhat[cc][2], (float)fhat[cc][3]);
    *(float4*)(op + 4) = make_float4((float)fhat[cc][4], (float)fhat[cc][5],
                                     (float)fhat[cc][6], (float)fhat[cc][7]);
  }
}

__global__ void finalize_total(const double* __restrict__ acc, float* __restrict__ total)
{
  if (threadIdx.x == 0 && blockIdx.x == 0) {
    double vq = 0.0, ent = 0.0;
    for (int si = 0; si < 6; ++si) {
      vq += acc[si * 18 + 0];
      double pse = acc[si * 18 + 1] / (double)BHW;
      double ce = 0.0;
      for (int cc = 0; cc < 16; ++cc) {
        double ap0 = acc[si * 18 + 2 + cc] / (double)BHW;
        double ap1 = 1.0 - ap0;
        ce -= ap0 * log(ap0 + 1e-5) + ap1 * log(ap1 + 1e-5);
      }
      ent += pse - ce;
    }
    *total = (float)(1.25 * vq / ((double)NELEM * 6.0) + (0.1 / 6.0) * ent);
  }
}

extern "C" void kernel_launch(void* const* d_in, const int* in_sizes, int n_in,
                              void* d_out, int out_size, void* d_ws, size_t ws_size,
                              hipStream_t stream)
{
  const float* f     = (const float*)d_in[0];
  const float* phi_w = (const float*)d_in[1];
  const float* phi_b = (const float*)d_in[2];
  float* out   = (float*)d_out;
  float* fhi   = out;                 // fully overwritten
  float* total = out + NELEM;
  float* hist  = out + NELEM + 1;     // 6*65536
  double* acc  = (double*)d_ws;       // 108 doubles

  hipMemsetAsync((void*)(out + NELEM), 0, (size_t)(1 + 6 * VOCAB) * sizeof(float), stream);
  hipMemsetAsync(d_ws, 0, 1024, stream);

  lfq_all<<<256, 512, 0, stream>>>(f, phi_w, phi_b, fhi, hist, acc);
  finalize_total<<<1, 64, 0, stream>>>(acc, total);
}